// Round 2
// baseline (529.692 us; speedup 1.0000x reference)
//
#include <hip/hip_runtime.h>
#include <hip/hip_bf16.h>

#define C_NUM 100000
#define D_EMB 512
#define N_BATCH 512
#define SCALE_F 30.0f
#define MARGIN_F 0.4f
#define H_F 0.333f
#define NTILES 1563          // ceil(100000/64)
#define GRID_MAIN 512        // persistent blocks, 2/CU

typedef __attribute__((ext_vector_type(8))) short bf16x8;
typedef __attribute__((ext_vector_type(4))) short bf16x4;
typedef __attribute__((ext_vector_type(4))) float f32x4;

static __device__ __forceinline__ short f2bf(float f) {
  __hip_bfloat16 h = __float2bfloat16(f);
  union { __hip_bfloat16 b; short s; } u;
  u.b = h;
  return u.s;
}

// ---------------------------------------------------------------------------
// Kernel 1: per-row L2 norm of embeddings; write unit-normalized rows as bf16.
// ---------------------------------------------------------------------------
__global__ __launch_bounds__(64) void k_rownorm(const float* __restrict__ emb,
                                                short* __restrict__ Aunit,
                                                float* __restrict__ norms) {
  const int i = blockIdx.x;
  const int l = threadIdx.x;
  const f32x4* row = reinterpret_cast<const f32x4*>(emb + (size_t)i * D_EMB);
  f32x4 v0 = row[l];
  f32x4 v1 = row[l + 64];
  float ss = v0[0]*v0[0] + v0[1]*v0[1] + v0[2]*v0[2] + v0[3]*v0[3]
           + v1[0]*v1[0] + v1[1]*v1[1] + v1[2]*v1[2] + v1[3]*v1[3];
#pragma unroll
  for (int m = 1; m < 64; m <<= 1) ss += __shfl_xor(ss, m);
  float nrm = sqrtf(ss);
  float inv = 1.0f / nrm;
  bf16x4 o0, o1;
#pragma unroll
  for (int q = 0; q < 4; ++q) { o0[q] = f2bf(v0[q] * inv); o1[q] = f2bf(v1[q] * inv); }
  bf16x4* dst = reinterpret_cast<bf16x4*>(Aunit + (size_t)i * D_EMB);
  dst[l] = o0;
  dst[l + 64] = o1;
  if (l == 0) norms[i] = nrm;
}

// ---------------------------------------------------------------------------
// Kernel 2: batch mean / unbiased std of norms -> adaptive margin per row.
// ---------------------------------------------------------------------------
__global__ __launch_bounds__(512) void k_stats(const float* __restrict__ norms,
                                               float* __restrict__ marg) {
  __shared__ float red[8];
  const int t = threadIdx.x;
  const int lane = t & 63, wid = t >> 6;
  float x = norms[t];
  float s = x;
#pragma unroll
  for (int m = 1; m < 64; m <<= 1) s += __shfl_xor(s, m);
  if (lane == 0) red[wid] = s;
  __syncthreads();
  float tot = 0.f;
#pragma unroll
  for (int q = 0; q < 8; ++q) tot += red[q];
  const float mean = tot / 512.f;
  __syncthreads();
  float d = x - mean;
  float s2 = d * d;
#pragma unroll
  for (int m = 1; m < 64; m <<= 1) s2 += __shfl_xor(s2, m);
  if (lane == 0) red[wid] = s2;
  __syncthreads();
  float tot2 = 0.f;
#pragma unroll
  for (int q = 0; q < 8; ++q) tot2 += red[q];
  const float stdv = sqrtf(tot2 / 511.f);   // ddof=1
  float msc = (x - mean) / (stdv + H_F);
  msc = fminf(1.f, fmaxf(-1.f, msc));
  marg[t] = MARGIN_F * (1.f + msc);
}

// ---------------------------------------------------------------------------
// Kernel 3: main. Persistent blocks; each loops over class tiles.
// Per tile: stage 64x512 weight tile bf16 into LDS (XOR swizzle, fused
// per-class rsqrt(sumsq)); 8 waves x 4x4 frags of mfma_f32_16x16x32_bf16;
// epilogue accumulates exp-sums in REGISTERS across tiles; one partial
// row-vector store per block at the end. No atomics.
// ---------------------------------------------------------------------------
__global__ __launch_bounds__(512, 4) void k_main(const short* __restrict__ Aunit,
                                                 const float* __restrict__ weight,
                                                 const int* __restrict__ labels,
                                                 const float* __restrict__ marg,
                                                 float* __restrict__ partial,
                                                 float* __restrict__ tlogit) {
  __shared__ alignas(16) short Bs[64 * 512];   // 64 KiB bf16 weight tile
  __shared__ float winv[64];
  __shared__ float rowsum[512];

  const int tid = threadIdx.x;
  char* BsB = reinterpret_cast<char*>(Bs);

  const int wid = tid >> 6;        // 0..7
  const int lane = tid & 63;
  const int rbase = wid * 64;
  const int lhi = lane >> 4;       // 0..3
  const int llo = lane & 15;

  // staging thread roles (constant across tiles)
  const int sc = tid >> 3;         // class within tile, 0..63
  const int sj = tid & 7;          // 8 threads per class

  // per-thread epilogue row ids + labels (constant across tiles)
  int labr[4][4];
#pragma unroll
  for (int mi = 0; mi < 4; ++mi)
#pragma unroll
    for (int reg = 0; reg < 4; ++reg)
      labr[mi][reg] = labels[rbase + mi * 16 + lhi * 4 + reg];

  float es[4][4];
#pragma unroll
  for (int mi = 0; mi < 4; ++mi)
#pragma unroll
    for (int q = 0; q < 4; ++q) es[mi][q] = 0.f;

  for (int tile = blockIdx.x; tile < NTILES; tile += GRID_MAIN) {
    const int c0 = tile * 64;

    // ---- stage B tile + per-class sumsq ----
    {
      const int gc = c0 + sc;
      const bool valid = gc < C_NUM;
      const f32x4* wrow = reinterpret_cast<const f32x4*>(weight + (size_t)gc * D_EMB);
      float ss = 0.f;
#pragma unroll
      for (int ii = 0; ii < 16; ++ii) {
        const int k4 = ii * 8 + sj;   // float4 index within row, 0..127
        f32x4 v;
        if (valid) v = wrow[k4];
        else       { v[0] = 0.f; v[1] = 0.f; v[2] = 0.f; v[3] = 0.f; }
        ss += v[0]*v[0] + v[1]*v[1] + v[2]*v[2] + v[3]*v[3];
        bf16x4 b;
#pragma unroll
        for (int q = 0; q < 4; ++q) b[q] = f2bf(v[q]);
        int byte = sc * 1024 + k4 * 8;
        byte ^= (sc & 7) << 4;                  // XOR swizzle
        *reinterpret_cast<bf16x4*>(BsB + byte) = b;
      }
      ss += __shfl_xor(ss, 1);
      ss += __shfl_xor(ss, 2);
      ss += __shfl_xor(ss, 4);
      if (sj == 0) winv[sc] = (valid && ss > 0.f) ? rsqrtf(ss) : 0.f;
    }
    __syncthreads();

    // ---- MFMA K-loop ----
    f32x4 acc[4][4];
#pragma unroll
    for (int mi = 0; mi < 4; ++mi)
#pragma unroll
      for (int ni = 0; ni < 4; ++ni)
#pragma unroll
        for (int q = 0; q < 4; ++q) acc[mi][ni][q] = 0.f;

    for (int k0 = 0; k0 < 512; k0 += 32) {
      const int ka = k0 + lhi * 8;
      bf16x8 a[4], b[4];
#pragma unroll
      for (int mi = 0; mi < 4; ++mi) {
        const int r = rbase + mi * 16 + llo;
        a[mi] = *reinterpret_cast<const bf16x8*>(Aunit + (size_t)r * D_EMB + ka);
      }
#pragma unroll
      for (int ni = 0; ni < 4; ++ni) {
        const int cc = ni * 16 + llo;
        int byte = cc * 1024 + ka * 2;
        byte ^= (cc & 7) << 4;
        b[ni] = *reinterpret_cast<const bf16x8*>(BsB + byte);
      }
#pragma unroll
      for (int mi = 0; mi < 4; ++mi)
#pragma unroll
        for (int ni = 0; ni < 4; ++ni)
          acc[mi][ni] = __builtin_amdgcn_mfma_f32_16x16x32_bf16(a[mi], b[ni], acc[mi][ni], 0, 0, 0);
    }

    // ---- epilogue: margin at label, exp-sum per row (regs, no LDS/atomics) ----
    float wv[4];
#pragma unroll
    for (int ni = 0; ni < 4; ++ni) wv[ni] = winv[ni * 16 + llo];

#pragma unroll
    for (int mi = 0; mi < 4; ++mi) {
#pragma unroll
      for (int ni = 0; ni < 4; ++ni) {
        const int gcc = c0 + ni * 16 + llo;
        const bool vcol = gcc < C_NUM;
#pragma unroll
        for (int reg = 0; reg < 4; ++reg) {
          const float cosv = acc[mi][ni][reg] * wv[ni];
          float logit = SCALE_F * cosv;
          if (labr[mi][reg] == gcc) {
            const int R = rbase + mi * 16 + lhi * 4 + reg;
            float ct = fminf(1.f, fmaxf(-1.f, cosv));
            float lt = SCALE_F * cosf(acosf(ct) + marg[R]);
            logit = lt;
            tlogit[R] = lt;
          }
          es[mi][reg] += vcol ? __expf(logit) : 0.f;
        }
      }
    }
    __syncthreads();   // before next stage overwrites Bs/winv
  }

  // ---- per-block partial row sums (no atomics) ----
#pragma unroll
  for (int mi = 0; mi < 4; ++mi)
#pragma unroll
    for (int reg = 0; reg < 4; ++reg) {
      float v = es[mi][reg];
      v += __shfl_xor(v, 1);
      v += __shfl_xor(v, 2);
      v += __shfl_xor(v, 4);
      v += __shfl_xor(v, 8);
      if (llo == 0) rowsum[rbase + mi * 16 + lhi * 4 + reg] = v;
    }
  __syncthreads();
  partial[(size_t)blockIdx.x * N_BATCH + tid] = rowsum[tid];
}

// ---------------------------------------------------------------------------
// Kernel 4: loss = mean(log(sum_b partial[b][row]) - target_logit)
// ---------------------------------------------------------------------------
__global__ __launch_bounds__(512) void k_final(const float* __restrict__ partial,
                                               const float* __restrict__ tlogit,
                                               float* __restrict__ out) {
  __shared__ float red[8];
  const int t = threadIdx.x;
  const int lane = t & 63, wid = t >> 6;
  float s0 = 0.f, s1 = 0.f, s2 = 0.f, s3 = 0.f;
  for (int b = 0; b < GRID_MAIN; b += 4) {
    s0 += partial[(size_t)(b + 0) * N_BATCH + t];
    s1 += partial[(size_t)(b + 1) * N_BATCH + t];
    s2 += partial[(size_t)(b + 2) * N_BATCH + t];
    s3 += partial[(size_t)(b + 3) * N_BATCH + t];
  }
  float v = logf((s0 + s1) + (s2 + s3)) - tlogit[t];
#pragma unroll
  for (int m = 1; m < 64; m <<= 1) v += __shfl_xor(v, m);
  if (lane == 0) red[wid] = v;
  __syncthreads();
  if (t == 0) {
    float tot = 0.f;
#pragma unroll
    for (int q = 0; q < 8; ++q) tot += red[q];
    out[0] = tot / 512.f;
  }
}

extern "C" void kernel_launch(void* const* d_in, const int* in_sizes, int n_in,
                              void* d_out, int out_size, void* d_ws, size_t ws_size,
                              hipStream_t stream) {
  const float* emb    = (const float*)d_in[0];
  const int*   labels = (const int*)d_in[1];
  const float* weight = (const float*)d_in[2];
  float* out = (float*)d_out;

  char* ws = (char*)d_ws;
  short* Aunit   = (short*)ws;                        // 512*512*2 = 524288 B
  float* norms   = (float*)(ws + 524288);             // 2 KiB
  float* marg    = (float*)(ws + 524288 + 2048);      // 2 KiB
  float* tlog    = (float*)(ws + 524288 + 4096);      // 2 KiB
  float* partial = (float*)(ws + 524288 + 6144);      // 512*512*4 = 1 MiB

  k_rownorm<<<N_BATCH, 64, 0, stream>>>(emb, Aunit, norms);
  k_stats<<<1, 512, 0, stream>>>(norms, marg);
  k_main<<<GRID_MAIN, 512, 0, stream>>>(Aunit, weight, labels, marg, partial, tlog);
  k_final<<<1, 512, 0, stream>>>(partial, tlog, out);
}

// Round 3
// 235.268 us; speedup vs baseline: 2.2514x; 2.2514x over previous
//
#include <hip/hip_runtime.h>
#include <hip/hip_bf16.h>

#define C_NUM 100000
#define D_EMB 512
#define N_BATCH 512
#define SCALE_F 30.0f
#define MARGIN_F 0.4f
#define H_F 0.333f
#define NTILES 1563          // ceil(100000/64)

typedef __attribute__((ext_vector_type(8))) short bf16x8;
typedef __attribute__((ext_vector_type(4))) short bf16x4;
typedef __attribute__((ext_vector_type(4))) float f32x4;

static __device__ __forceinline__ short f2bf(float f) {
  __hip_bfloat16 h = __float2bfloat16(f);
  union { __hip_bfloat16 b; short s; } u;
  u.b = h;
  return u.s;
}

// ---------------------------------------------------------------------------
// Kernel 1: per-row L2 norm of embeddings; write unit-normalized rows as bf16.
// ---------------------------------------------------------------------------
__global__ __launch_bounds__(64) void k_rownorm(const float* __restrict__ emb,
                                                short* __restrict__ Aunit,
                                                float* __restrict__ norms) {
  const int i = blockIdx.x;
  const int l = threadIdx.x;
  const f32x4* row = reinterpret_cast<const f32x4*>(emb + (size_t)i * D_EMB);
  f32x4 v0 = row[l];
  f32x4 v1 = row[l + 64];
  float ss = v0[0]*v0[0] + v0[1]*v0[1] + v0[2]*v0[2] + v0[3]*v0[3]
           + v1[0]*v1[0] + v1[1]*v1[1] + v1[2]*v1[2] + v1[3]*v1[3];
#pragma unroll
  for (int m = 1; m < 64; m <<= 1) ss += __shfl_xor(ss, m);
  float nrm = sqrtf(ss);
  float inv = 1.0f / nrm;
  bf16x4 o0, o1;
#pragma unroll
  for (int q = 0; q < 4; ++q) { o0[q] = f2bf(v0[q] * inv); o1[q] = f2bf(v1[q] * inv); }
  bf16x4* dst = reinterpret_cast<bf16x4*>(Aunit + (size_t)i * D_EMB);
  dst[l] = o0;
  dst[l + 64] = o1;
  if (l == 0) norms[i] = nrm;
}

// ---------------------------------------------------------------------------
// Kernel 2: batch mean / unbiased std of norms -> adaptive margin per row.
// ---------------------------------------------------------------------------
__global__ __launch_bounds__(512) void k_stats(const float* __restrict__ norms,
                                               float* __restrict__ marg) {
  __shared__ float red[8];
  const int t = threadIdx.x;
  const int lane = t & 63, wid = t >> 6;
  float x = norms[t];
  float s = x;
#pragma unroll
  for (int m = 1; m < 64; m <<= 1) s += __shfl_xor(s, m);
  if (lane == 0) red[wid] = s;
  __syncthreads();
  float tot = 0.f;
#pragma unroll
  for (int q = 0; q < 8; ++q) tot += red[q];
  const float mean = tot / 512.f;
  __syncthreads();
  float d = x - mean;
  float s2 = d * d;
#pragma unroll
  for (int m = 1; m < 64; m <<= 1) s2 += __shfl_xor(s2, m);
  if (lane == 0) red[wid] = s2;
  __syncthreads();
  float tot2 = 0.f;
#pragma unroll
  for (int q = 0; q < 8; ++q) tot2 += red[q];
  const float stdv = sqrtf(tot2 / 511.f);   // ddof=1
  float msc = (x - mean) / (stdv + H_F);
  msc = fminf(1.f, fmaxf(-1.f, msc));
  marg[t] = MARGIN_F * (1.f + msc);
}

// ---------------------------------------------------------------------------
// Kernel 3: main. One block per 64-class tile (short register lifetimes — no
// spills). Stage 64x512 weight tile bf16 into LDS (XOR swizzle, fused
// per-class rsqrt(sumsq)); 8 waves x 4x4 frags of mfma_f32_16x16x32_bf16;
// epilogue: margin at label, per-row exp-sums -> one coalesced partial
// row-vector store per block. No atomics, no cross-K-loop live registers.
// ---------------------------------------------------------------------------
__global__ __launch_bounds__(512) void k_main(const short* __restrict__ Aunit,
                                              const float* __restrict__ weight,
                                              const int* __restrict__ labels,
                                              const float* __restrict__ marg,
                                              float* __restrict__ partial,
                                              float* __restrict__ tlogit) {
  __shared__ alignas(16) short Bs[64 * 512];   // 64 KiB bf16 weight tile
  __shared__ float winv[64];
  __shared__ float rowsum[512];

  const int tid = threadIdx.x;
  const int c0 = blockIdx.x * 64;
  char* BsB = reinterpret_cast<char*>(Bs);

  // ---- stage B tile + per-class sumsq ----
  {
    const int sc = tid >> 3;         // class within tile, 0..63
    const int sj = tid & 7;          // 8 threads per class
    const int gc = c0 + sc;
    const bool valid = gc < C_NUM;
    const f32x4* wrow = reinterpret_cast<const f32x4*>(weight + (size_t)gc * D_EMB);
    float ss = 0.f;
#pragma unroll
    for (int ii = 0; ii < 16; ++ii) {
      const int k4 = ii * 8 + sj;    // float4 index within row, 0..127
      f32x4 v;
      if (valid) v = wrow[k4];
      else       { v[0] = 0.f; v[1] = 0.f; v[2] = 0.f; v[3] = 0.f; }
      ss += v[0]*v[0] + v[1]*v[1] + v[2]*v[2] + v[3]*v[3];
      bf16x4 b;
#pragma unroll
      for (int q = 0; q < 4; ++q) b[q] = f2bf(v[q]);
      int byte = sc * 1024 + k4 * 8;
      byte ^= (sc & 7) << 4;                  // XOR swizzle (G4)
      *reinterpret_cast<bf16x4*>(BsB + byte) = b;
    }
    ss += __shfl_xor(ss, 1);
    ss += __shfl_xor(ss, 2);
    ss += __shfl_xor(ss, 4);
    if (sj == 0) winv[sc] = (valid && ss > 0.f) ? rsqrtf(ss) : 0.f;
  }
  __syncthreads();

  // ---- MFMA K-loop ----
  const int wid = tid >> 6;        // 0..7
  const int lane = tid & 63;
  const int rbase = wid * 64;
  const int lhi = lane >> 4;       // 0..3
  const int llo = lane & 15;

  f32x4 acc[4][4];
#pragma unroll
  for (int mi = 0; mi < 4; ++mi)
#pragma unroll
    for (int ni = 0; ni < 4; ++ni)
#pragma unroll
      for (int q = 0; q < 4; ++q) acc[mi][ni][q] = 0.f;

  for (int k0 = 0; k0 < 512; k0 += 32) {
    const int ka = k0 + lhi * 8;
    bf16x8 a[4], b[4];
#pragma unroll
    for (int mi = 0; mi < 4; ++mi) {
      const int r = rbase + mi * 16 + llo;
      a[mi] = *reinterpret_cast<const bf16x8*>(Aunit + (size_t)r * D_EMB + ka);
    }
#pragma unroll
    for (int ni = 0; ni < 4; ++ni) {
      const int cc = ni * 16 + llo;
      int byte = cc * 1024 + ka * 2;
      byte ^= (cc & 7) << 4;
      b[ni] = *reinterpret_cast<const bf16x8*>(BsB + byte);
    }
#pragma unroll
    for (int mi = 0; mi < 4; ++mi)
#pragma unroll
      for (int ni = 0; ni < 4; ++ni)
        acc[mi][ni] = __builtin_amdgcn_mfma_f32_16x16x32_bf16(a[mi], b[ni], acc[mi][ni], 0, 0, 0);
  }

  // ---- epilogue: margin at label, exp-sum per row ----
  float es[4][4];
#pragma unroll
  for (int mi = 0; mi < 4; ++mi)
#pragma unroll
    for (int q = 0; q < 4; ++q) es[mi][q] = 0.f;

#pragma unroll
  for (int mi = 0; mi < 4; ++mi) {
#pragma unroll
    for (int ni = 0; ni < 4; ++ni) {
      const int ccol = ni * 16 + llo;
      const int gcc = c0 + ccol;
      const float wv = winv[ccol];
      const bool vcol = gcc < C_NUM;
#pragma unroll
      for (int reg = 0; reg < 4; ++reg) {
        const int R = rbase + mi * 16 + lhi * 4 + reg;
        const float cosv = acc[mi][ni][reg] * wv;
        float logit = SCALE_F * cosv;
        if (labels[R] == gcc) {
          float ct = fminf(1.f, fmaxf(-1.f, cosv));
          float lt = SCALE_F * cosf(acosf(ct) + marg[R]);
          logit = lt;
          tlogit[R] = lt;
        }
        es[mi][reg] += vcol ? __expf(logit) : 0.f;
      }
    }
  }

#pragma unroll
  for (int mi = 0; mi < 4; ++mi)
#pragma unroll
    for (int reg = 0; reg < 4; ++reg) {
      float v = es[mi][reg];
      v += __shfl_xor(v, 1);
      v += __shfl_xor(v, 2);
      v += __shfl_xor(v, 4);
      v += __shfl_xor(v, 8);
      if (llo == 0) rowsum[rbase + mi * 16 + lhi * 4 + reg] = v;
    }
  __syncthreads();
  partial[(size_t)blockIdx.x * N_BATCH + tid] = rowsum[tid];
}

// ---------------------------------------------------------------------------
// Kernel 4: per-row reduce over tiles: term[r] = log(sum_b partial[b][r]) - tlogit[r]
// One wave per row.
// ---------------------------------------------------------------------------
__global__ __launch_bounds__(64) void k_reduce(const float* __restrict__ partial,
                                               const float* __restrict__ tlogit,
                                               float* __restrict__ term) {
  const int r = blockIdx.x;
  const int l = threadIdx.x;
  float s = 0.f;
  for (int b = l; b < NTILES; b += 64)
    s += partial[(size_t)b * N_BATCH + r];
#pragma unroll
  for (int m = 1; m < 64; m <<= 1) s += __shfl_xor(s, m);
  if (l == 0) term[r] = logf(s) - tlogit[r];
}

// ---------------------------------------------------------------------------
// Kernel 5: loss = mean(term)
// ---------------------------------------------------------------------------
__global__ __launch_bounds__(512) void k_final(const float* __restrict__ term,
                                               float* __restrict__ out) {
  __shared__ float red[8];
  const int t = threadIdx.x;
  const int lane = t & 63, wid = t >> 6;
  float v = term[t];
#pragma unroll
  for (int m = 1; m < 64; m <<= 1) v += __shfl_xor(v, m);
  if (lane == 0) red[wid] = v;
  __syncthreads();
  if (t == 0) {
    float tot = 0.f;
#pragma unroll
    for (int q = 0; q < 8; ++q) tot += red[q];
    out[0] = tot / 512.f;
  }
}

extern "C" void kernel_launch(void* const* d_in, const int* in_sizes, int n_in,
                              void* d_out, int out_size, void* d_ws, size_t ws_size,
                              hipStream_t stream) {
  const float* emb    = (const float*)d_in[0];
  const int*   labels = (const int*)d_in[1];
  const float* weight = (const float*)d_in[2];
  float* out = (float*)d_out;

  char* ws = (char*)d_ws;
  short* Aunit   = (short*)ws;                        // 512*512*2 = 524288 B
  float* norms   = (float*)(ws + 524288);             // 2 KiB
  float* marg    = (float*)(ws + 524288 + 2048);      // 2 KiB
  float* tlog    = (float*)(ws + 524288 + 4096);      // 2 KiB
  float* term    = (float*)(ws + 524288 + 6144);      // 2 KiB
  float* partial = (float*)(ws + 524288 + 8192);      // 1563*512*4 = 3201024 B

  k_rownorm<<<N_BATCH, 64, 0, stream>>>(emb, Aunit, norms);
  k_stats<<<1, 512, 0, stream>>>(norms, marg);
  k_main<<<NTILES, 512, 0, stream>>>(Aunit, weight, labels, marg, partial, tlog);
  k_reduce<<<N_BATCH, 64, 0, stream>>>(partial, tlog, term);
  k_final<<<1, 512, 0, stream>>>(term, out);
}

// Round 5
// 185.177 us; speedup vs baseline: 2.8605x; 1.2705x over previous
//
#include <hip/hip_runtime.h>
#include <hip/hip_bf16.h>

#define C_NUM 100000
#define D_EMB 512
#define N_BATCH 512
#define SCALE_F 30.0f
#define MARGIN_F 0.4f
#define H_F 0.333f
#define NTILES 1563          // ceil(100000/64)

typedef __attribute__((ext_vector_type(8))) short bf16x8;
typedef __attribute__((ext_vector_type(4))) short bf16x4;
typedef __attribute__((ext_vector_type(4))) float f32x4;
typedef __attribute__((ext_vector_type(16))) float f32x16;

static __device__ __forceinline__ short f2bf(float f) {
  __hip_bfloat16 h = __float2bfloat16(f);
  union { __hip_bfloat16 b; short s; } u;
  u.b = h;
  return u.s;
}

// ---------------------------------------------------------------------------
// Kernel 1: per-row L2 norm of embeddings; write unit-normalized rows as bf16.
// ---------------------------------------------------------------------------
__global__ __launch_bounds__(64) void k_rownorm(const float* __restrict__ emb,
                                                short* __restrict__ Aunit,
                                                float* __restrict__ norms) {
  const int i = blockIdx.x;
  const int l = threadIdx.x;
  const f32x4* row = reinterpret_cast<const f32x4*>(emb + (size_t)i * D_EMB);
  f32x4 v0 = row[l];
  f32x4 v1 = row[l + 64];
  float ss = v0[0]*v0[0] + v0[1]*v0[1] + v0[2]*v0[2] + v0[3]*v0[3]
           + v1[0]*v1[0] + v1[1]*v1[1] + v1[2]*v1[2] + v1[3]*v1[3];
#pragma unroll
  for (int m = 1; m < 64; m <<= 1) ss += __shfl_xor(ss, m);
  float nrm = sqrtf(ss);
  float inv = 1.0f / nrm;
  bf16x4 o0, o1;
#pragma unroll
  for (int q = 0; q < 4; ++q) { o0[q] = f2bf(v0[q] * inv); o1[q] = f2bf(v1[q] * inv); }
  bf16x4* dst = reinterpret_cast<bf16x4*>(Aunit + (size_t)i * D_EMB);
  dst[l] = o0;
  dst[l + 64] = o1;
  if (l == 0) norms[i] = nrm;
}

// ---------------------------------------------------------------------------
// Kernel 2: batch mean / unbiased std of norms -> adaptive margin per row.
// ---------------------------------------------------------------------------
__global__ __launch_bounds__(512) void k_stats(const float* __restrict__ norms,
                                               float* __restrict__ marg) {
  __shared__ float red[8];
  const int t = threadIdx.x;
  const int lane = t & 63, wid = t >> 6;
  float x = norms[t];
  float s = x;
#pragma unroll
  for (int m = 1; m < 64; m <<= 1) s += __shfl_xor(s, m);
  if (lane == 0) red[wid] = s;
  __syncthreads();
  float tot = 0.f;
#pragma unroll
  for (int q = 0; q < 8; ++q) tot += red[q];
  const float mean = tot / 512.f;
  __syncthreads();
  float d = x - mean;
  float s2 = d * d;
#pragma unroll
  for (int m = 1; m < 64; m <<= 1) s2 += __shfl_xor(s2, m);
  if (lane == 0) red[wid] = s2;
  __syncthreads();
  float tot2 = 0.f;
#pragma unroll
  for (int q = 0; q < 8; ++q) tot2 += red[q];
  const float stdv = sqrtf(tot2 / 511.f);   // ddof=1
  float msc = (x - mean) / (stdv + H_F);
  msc = fminf(1.f, fmaxf(-1.f, msc));
  marg[t] = MARGIN_F * (1.f + msc);
}

// ---------------------------------------------------------------------------
// Kernel 3: main. One block per 64-class tile. 32x32x16 MFMA, 2x2 frags per
// wave: live set ~95 regs -> no spill at the 128-reg/2-blocks-per-CU budget.
// LDS XOR swizzle (row&15)<<4 applied to the FULL byte offset on both write
// and read (round-4 bug: read applied XOR to base then added k -> wrong bytes).
// ---------------------------------------------------------------------------
__global__ __launch_bounds__(512, 4) void k_main(const short* __restrict__ Aunit,
                                                 const float* __restrict__ weight,
                                                 const int* __restrict__ labels,
                                                 const float* __restrict__ marg,
                                                 float* __restrict__ partial,
                                                 float* __restrict__ tlogit) {
  __shared__ alignas(16) short Bs[64 * 512];   // 64 KiB bf16 weight tile
  __shared__ float winv[64];
  __shared__ float rowsum[512];

  const int tid = threadIdx.x;
  const int c0 = blockIdx.x * 64;
  char* BsB = reinterpret_cast<char*>(Bs);

  // ---- stage B tile + per-class sumsq ----
  {
    const int sc = tid >> 3;         // class within tile, 0..63
    const int sj = tid & 7;          // 8 threads per class
    const int gc = c0 + sc;
    const bool valid = gc < C_NUM;
    const f32x4* wrow = reinterpret_cast<const f32x4*>(weight + (size_t)gc * D_EMB);
    float ss = 0.f;
#pragma unroll
    for (int ii = 0; ii < 16; ++ii) {
      const int k4 = ii * 8 + sj;    // float4 index within row, 0..127
      f32x4 v;
      if (valid) v = wrow[k4];
      else       { v[0] = 0.f; v[1] = 0.f; v[2] = 0.f; v[3] = 0.f; }
      ss += v[0]*v[0] + v[1]*v[1] + v[2]*v[2] + v[3]*v[3];
      bf16x4 b;
#pragma unroll
      for (int q = 0; q < 4; ++q) b[q] = f2bf(v[q]);
      const int byte = (sc * 1024 + k4 * 8) ^ ((sc & 15) << 4);  // XOR on full offset
      *reinterpret_cast<bf16x4*>(BsB + byte) = b;
    }
    ss += __shfl_xor(ss, 1);
    ss += __shfl_xor(ss, 2);
    ss += __shfl_xor(ss, 4);
    if (sj == 0) winv[sc] = (valid && ss > 0.f) ? rsqrtf(ss) : 0.f;
  }
  __syncthreads();

  // ---- MFMA K-loop: 32x32x16, 2x2 frags per wave ----
  const int wid = tid >> 6;        // 0..7
  const int lane = tid & 63;
  const int rbase = wid * 64;
  const int l31 = lane & 31;
  const int lhi = lane >> 5;       // 0..1

  f32x16 acc00, acc01, acc10, acc11;
#pragma unroll
  for (int q = 0; q < 16; ++q) { acc00[q] = 0.f; acc01[q] = 0.f; acc10[q] = 0.f; acc11[q] = 0.f; }

  const short* arow0 = Aunit + (size_t)(rbase + l31) * D_EMB;        // rows mi=0
  const short* arow1 = Aunit + (size_t)(rbase + 32 + l31) * D_EMB;   // rows mi=1
  const int swz = (l31 & 15) << 4;
  const int cbase0 = l31 * 1024;          // class l31
  const int cbase1 = (l31 + 32) * 1024;   // class l31+32

  for (int k0 = 0; k0 < 512; k0 += 32) {
#pragma unroll
    for (int kk = 0; kk < 2; ++kk) {
      const int ka = k0 + kk * 16 + lhi * 8;     // 8 bf16 along K per lane
      bf16x8 a0 = *reinterpret_cast<const bf16x8*>(arow0 + ka);
      bf16x8 a1 = *reinterpret_cast<const bf16x8*>(arow1 + ka);
      bf16x8 b0 = *reinterpret_cast<const bf16x8*>(BsB + ((cbase0 + ka * 2) ^ swz));
      bf16x8 b1 = *reinterpret_cast<const bf16x8*>(BsB + ((cbase1 + ka * 2) ^ swz));
      acc00 = __builtin_amdgcn_mfma_f32_32x32x16_bf16(a0, b0, acc00, 0, 0, 0);
      acc01 = __builtin_amdgcn_mfma_f32_32x32x16_bf16(a0, b1, acc01, 0, 0, 0);
      acc10 = __builtin_amdgcn_mfma_f32_32x32x16_bf16(a1, b0, acc10, 0, 0, 0);
      acc11 = __builtin_amdgcn_mfma_f32_32x32x16_bf16(a1, b1, acc11, 0, 0, 0);
    }
  }

  // ---- epilogue: margin at label, exp-sum per row ----
  // C/D layout (m74/m101): col = lane&31, row = (reg&3) + 8*(reg>>2) + 4*(lane>>5)
  const float wv0 = winv[l31];
  const float wv1 = winv[32 + l31];
  const int gcc0 = c0 + l31;
  const int gcc1 = c0 + 32 + l31;
  const bool v0ok = gcc0 < C_NUM;
  const bool v1ok = gcc1 < C_NUM;

#pragma unroll
  for (int mi = 0; mi < 2; ++mi) {
#pragma unroll
    for (int r = 0; r < 16; ++r) {
      const int rowf = (r & 3) + 8 * (r >> 2) + 4 * lhi;
      const int R = rbase + mi * 32 + rowf;
      const int lab = labels[R];
      float c0v = (mi == 0 ? acc00[r] : acc10[r]) * wv0;
      float c1v = (mi == 0 ? acc01[r] : acc11[r]) * wv1;
      float lg0 = SCALE_F * c0v;
      float lg1 = SCALE_F * c1v;
      if (lab == gcc0) {
        float ct = fminf(1.f, fmaxf(-1.f, c0v));
        float lt = SCALE_F * cosf(acosf(ct) + marg[R]);
        lg0 = lt; tlogit[R] = lt;
      }
      if (lab == gcc1) {
        float ct = fminf(1.f, fmaxf(-1.f, c1v));
        float lt = SCALE_F * cosf(acosf(ct) + marg[R]);
        lg1 = lt; tlogit[R] = lt;
      }
      float v = (v0ok ? __expf(lg0) : 0.f) + (v1ok ? __expf(lg1) : 0.f);
      v += __shfl_xor(v, 1);
      v += __shfl_xor(v, 2);
      v += __shfl_xor(v, 4);
      v += __shfl_xor(v, 8);
      v += __shfl_xor(v, 16);
      if (l31 == 0) rowsum[R] = v;
    }
  }
  __syncthreads();
  partial[(size_t)blockIdx.x * N_BATCH + tid] = rowsum[tid];
}

// ---------------------------------------------------------------------------
// Kernel 4: per-row reduce over tiles: term[r] = log(sum_b partial[b][r]) - tlogit[r]
// ---------------------------------------------------------------------------
__global__ __launch_bounds__(64) void k_reduce(const float* __restrict__ partial,
                                               const float* __restrict__ tlogit,
                                               float* __restrict__ term) {
  const int r = blockIdx.x;
  const int l = threadIdx.x;
  float s = 0.f;
  for (int b = l; b < NTILES; b += 64)
    s += partial[(size_t)b * N_BATCH + r];
#pragma unroll
  for (int m = 1; m < 64; m <<= 1) s += __shfl_xor(s, m);
  if (l == 0) term[r] = logf(s) - tlogit[r];
}

// ---------------------------------------------------------------------------
// Kernel 5: loss = mean(term)
// ---------------------------------------------------------------------------
__global__ __launch_bounds__(512) void k_final(const float* __restrict__ term,
                                               float* __restrict__ out) {
  __shared__ float red[8];
  const int t = threadIdx.x;
  const int lane = t & 63, wid = t >> 6;
  float v = term[t];
#pragma unroll
  for (int m = 1; m < 64; m <<= 1) v += __shfl_xor(v, m);
  if (lane == 0) red[wid] = v;
  __syncthreads();
  if (t == 0) {
    float tot = 0.f;
#pragma unroll
    for (int q = 0; q < 8; ++q) tot += red[q];
    out[0] = tot / 512.f;
  }
}

extern "C" void kernel_launch(void* const* d_in, const int* in_sizes, int n_in,
                              void* d_out, int out_size, void* d_ws, size_t ws_size,
                              hipStream_t stream) {
  const float* emb    = (const float*)d_in[0];
  const int*   labels = (const int*)d_in[1];
  const float* weight = (const float*)d_in[2];
  float* out = (float*)d_out;

  char* ws = (char*)d_ws;
  short* Aunit   = (short*)ws;                        // 512*512*2 = 524288 B
  float* norms   = (float*)(ws + 524288);             // 2 KiB
  float* marg    = (float*)(ws + 524288 + 2048);      // 2 KiB
  float* tlog    = (float*)(ws + 524288 + 4096);      // 2 KiB
  float* term    = (float*)(ws + 524288 + 6144);      // 2 KiB
  float* partial = (float*)(ws + 524288 + 8192);      // 1563*512*4 = 3201024 B

  k_rownorm<<<N_BATCH, 64, 0, stream>>>(emb, Aunit, norms);
  k_stats<<<1, 512, 0, stream>>>(norms, marg);
  k_main<<<NTILES, 512, 0, stream>>>(Aunit, weight, labels, marg, partial, tlog);
  k_reduce<<<N_BATCH, 64, 0, stream>>>(partial, tlog, term);
  k_final<<<1, 512, 0, stream>>>(term, out);
}